// Round 1
// baseline (1253.387 us; speedup 1.0000x reference)
//
#include <hip/hip_runtime.h>
#include <hip/hip_bf16.h>
#include <cstdint>
#include <cstddef>

// Problem constants
#define BB 2
#define SS 2048
#define DD 4096
#define HH 32
#define KVH 8
#define DH 128
#define KVD 1024
#define SCALE 0.08838834764831845f   // DH^-0.5

typedef __attribute__((ext_vector_type(8))) short short8;
typedef __attribute__((ext_vector_type(4))) float f32x4;

typedef __attribute__((address_space(1))) void GV;
typedef __attribute__((address_space(3))) void LV;

__device__ __forceinline__ void async16(const void* g, void* l) {
  __builtin_amdgcn_global_load_lds((GV*)g, (LV*)l, 16, 0, 0);
}

__device__ __forceinline__ unsigned short f2bf(float x) {
  union { float f; uint32_t u; } v; v.f = x;
  uint32_t r = (v.u + 0x7fffu + ((v.u >> 16) & 1u)) >> 16;
  return (unsigned short)r;
}
__device__ __forceinline__ float bf2f(unsigned short b) {
  union { uint32_t u; float f; } v; v.u = ((uint32_t)b) << 16; return v.f;
}
__device__ __forceinline__ f32x4 mfma16(short8 a, short8 b, f32x4 c) {
  return __builtin_amdgcn_mfma_f32_16x16x32_bf16(a, b, c, 0, 0, 0);
}

// ---------------- cast fp32 -> bf16 (straight) ----------------
__global__ __launch_bounds__(256) void cast_bf16_kernel(
    const float* __restrict__ in, unsigned short* __restrict__ out, int n4) {
  int i = blockIdx.x * 256 + threadIdx.x;
  if (i >= n4) return;
  float4 v = ((const float4*)in)[i];
  ushort4 o;
  o.x = f2bf(v.x); o.y = f2bf(v.y); o.z = f2bf(v.z); o.w = f2bf(v.w);
  ((ushort4*)out)[i] = o;
}

// ---------------- cast + transpose: (R x C) fp32 -> (C x R) bf16 ----------------
__global__ __launch_bounds__(256) void transpose_cast_kernel(
    const float* __restrict__ in, unsigned short* __restrict__ out, int R, int C) {
  __shared__ unsigned short tile[32][33];
  const int tx = threadIdx.x, ty = threadIdx.y;       // block (32,8)
  const int c0 = blockIdx.x * 32, r0 = blockIdx.y * 32;
  for (int i = ty; i < 32; i += 8)
    tile[i][tx] = f2bf(in[(size_t)(r0 + i) * C + c0 + tx]);
  __syncthreads();
  for (int i = ty; i < 32; i += 8)
    out[(size_t)(c0 + i) * R + r0 + tx] = tile[tx][i];
}

// ---------------- GEMM: C[M,N] = A[M,K] * Bt[N,K]^T  (bf16 in, fp32 acc) ----------
// m97 structure: BM=BN=128, BK=32, 4 waves each 64x64, global_load_lds width 16.
template <typename OutT>
__global__ __launch_bounds__(256, 2) void gemm_bt(
    const unsigned short* __restrict__ A, const unsigned short* __restrict__ Bt,
    OutT* __restrict__ C, int M, int N, int K) {
  __shared__ __align__(16) unsigned short As[4096];  // [128][32]
  __shared__ __align__(16) unsigned short Bs[4096];  // [128][32]
  const int tid = threadIdx.x;
  const int wave = tid >> 6, lane = tid & 63, quad = lane >> 4, l16 = lane & 15;
  const int m0 = blockIdx.x * 128, n0 = blockIdx.y * 128;
  const int wm = (wave & 1) * 64, wn = (wave >> 1) * 64;
  f32x4 acc[4][4] = {};
  // staging map: thread t covers LDS elems [t*8, t*8+8) per issue => row t/4, col (t%4)*8
  const int sr = tid >> 2, sc = (tid & 3) * 8;
  const unsigned short* Ag = A + (size_t)(m0 + sr) * K + sc;
  const unsigned short* Bg = Bt + (size_t)(n0 + sr) * K + sc;
  unsigned short* AsW = As + wave * 512;
  unsigned short* BsW = Bs + wave * 512;
  for (int k0 = 0; k0 < K; k0 += 32) {
    __syncthreads();
    async16(Ag + k0, AsW);
    async16(Ag + (size_t)64 * K + k0, AsW + 2048);
    async16(Bg + k0, BsW);
    async16(Bg + (size_t)64 * K + k0, BsW + 2048);
    __syncthreads();
    short8 af[4], bf[4];
#pragma unroll
    for (int i = 0; i < 4; i++) {
      af[i] = *(const short8*)&As[(wm + i * 16 + l16) * 32 + quad * 8];
      bf[i] = *(const short8*)&Bs[(wn + i * 16 + l16) * 32 + quad * 8];
    }
#pragma unroll
    for (int mi = 0; mi < 4; mi++)
#pragma unroll
      for (int ni = 0; ni < 4; ni++)
        acc[mi][ni] = mfma16(af[mi], bf[ni], acc[mi][ni]);
  }
#pragma unroll
  for (int mi = 0; mi < 4; mi++)
#pragma unroll
    for (int ni = 0; ni < 4; ni++)
#pragma unroll
      for (int r = 0; r < 4; r++) {
        int row = m0 + wm + mi * 16 + quad * 4 + r;   // C/D: row=quad*4+reg
        int col = n0 + wn + ni * 16 + l16;            //      col=lane&15
        float v = acc[mi][ni][r];
        if constexpr (sizeof(OutT) == 4) C[(size_t)row * N + col] = v;
        else                             C[(size_t)row * N + col] = (OutT)f2bf(v);
      }
}

// ---------------- RMSNorm(q over 4096, k over 1024) + RoPE + V transpose --------
__global__ __launch_bounds__(256) void rmsnorm_rope_kernel(
    const unsigned short* __restrict__ qkv,
    const float* __restrict__ q_scale, const float* __restrict__ k_scale,
    const float* __restrict__ cosc, const float* __restrict__ sinc,
    unsigned short* __restrict__ qo,   // (B,H,S,DH)
    unsigned short* __restrict__ ko,   // (B,KVH,S,DH)
    unsigned short* __restrict__ vo)   // (B,KVH,DH,S)  transposed
{
  const int row = blockIdx.x;              // b*S + s
  const int b = row >> 11, s = row & 2047; // S=2048
  const int tid = threadIdx.x;
  const unsigned short* qr = qkv + (size_t)row * 6144;
  float sq = 0.f, sk = 0.f;
  for (int c = tid; c < 4096; c += 256) { float v = bf2f(qr[c]); sq += v * v; }
  for (int c = tid; c < 1024; c += 256) { float v = bf2f(qr[4096 + c]); sk += v * v; }
#pragma unroll
  for (int off = 32; off; off >>= 1) {
    sq += __shfl_down(sq, off, 64);
    sk += __shfl_down(sk, off, 64);
  }
  __shared__ float redq[4], redk[4];
  if ((tid & 63) == 0) { redq[tid >> 6] = sq; redk[tid >> 6] = sk; }
  __syncthreads();
  sq = redq[0] + redq[1] + redq[2] + redq[3];
  sk = redk[0] + redk[1] + redk[2] + redk[3];
  const float rq = rsqrtf(sq * (1.f / 4096.f) + 1e-6f);
  const float rk = rsqrtf(sk * (1.f / 1024.f) + 1e-6f);
  const float* cp = cosc + (size_t)row * 128;
  const float* sp = sinc + (size_t)row * 128;
  // Q: norm + rope
  for (int c = tid; c < 4096; c += 256) {
    int d = c & 127, hh = c >> 7;
    float v = bf2f(qr[c]) * rq * q_scale[c];
    int c2 = (d < 64) ? c + 64 : c - 64;
    float v2 = bf2f(qr[c2]) * rq * q_scale[c2];
    float rot = (d < 64) ? -v2 : v2;
    qo[((size_t)(b * HH + hh) * SS + s) * DH + d] = f2bf(v * cp[d] + rot * sp[d]);
  }
  // K: norm + rope
  for (int c = tid; c < 1024; c += 256) {
    int d = c & 127, hh = c >> 7;
    float v = bf2f(qr[4096 + c]) * rk * k_scale[c];
    int kc2 = (d < 64) ? c + 64 : c - 64;
    float v2 = bf2f(qr[4096 + kc2]) * rk * k_scale[kc2];
    float rot = (d < 64) ? -v2 : v2;
    ko[((size_t)(b * KVH + hh) * SS + s) * DH + d] = f2bf(v * cp[d] + rot * sp[d]);
  }
  // V: passthrough, transposed layout (B,KVH,DH,S)
  for (int c = tid; c < 1024; c += 256) {
    int d = c & 127, hh = c >> 7;
    vo[((size_t)(b * KVH + hh) * DH + d) * SS + s] = qr[5120 + c];
  }
}

// ---------------- Flash attention: causal, GQA 4:1 ----------------
// grid (S/64, B*H); 4 waves/block; wave w handles 16 q-rows.
__global__ __launch_bounds__(256, 2) void flash_attn(
    const unsigned short* __restrict__ Q,   // (B,H,S,DH)
    const unsigned short* __restrict__ Kr,  // (B,KVH,S,DH)
    const unsigned short* __restrict__ Vt,  // (B,KVH,DH,S)
    unsigned short* __restrict__ O)         // (B,S,H*DH)
{
  __shared__ __align__(16) unsigned short Ks[4096];   // [32 key][128 d]
  __shared__ __align__(16) unsigned short Vs[4096];   // [128 d][32 key]  (V^T tile)
  __shared__ __align__(16) unsigned short Ps[4][512]; // per-wave P: [16 m][32 k]
  const int tid = threadIdx.x, wave = tid >> 6, lane = tid & 63;
  const int quad = lane >> 4, l16 = lane & 15;
  const int bh = blockIdx.y, b = bh >> 5, h = bh & 31;
  const int kvh = h >> 2;                               // H/KVH = 4
  const int qbase = (gridDim.x - 1 - blockIdx.x) * 64;  // heavy blocks first
  const int qrow0 = qbase + wave * 16;
  const unsigned short* Qp = Q + ((size_t)(b * HH + h) * SS + qrow0 + l16) * DH;
  short8 qf[4];
#pragma unroll
  for (int c = 0; c < 4; c++) qf[c] = *(const short8*)(Qp + c * 32 + quad * 8);
  const unsigned short* Kg = Kr + (size_t)(b * KVH + kvh) * SS * DH;
  const unsigned short* Vg = Vt + (size_t)(b * KVH + kvh) * DH * SS;
  const unsigned short* KgT = Kg + (size_t)(tid >> 4) * DH + (tid & 15) * 8;
  const unsigned short* VgT = Vg + (size_t)(tid >> 2) * SS + (tid & 3) * 8;
  f32x4 o[8] = {};
  float m_i[4] = {-1e30f, -1e30f, -1e30f, -1e30f};
  float l_i[4] = {0.f, 0.f, 0.f, 0.f};
  const int nkt = (qbase + 64) >> 5;
  for (int kt = 0; kt < nkt; kt++) {
    const int k0 = kt * 32;
    __syncthreads();
    async16(KgT + (size_t)k0 * DH, Ks + wave * 512);
    async16(KgT + (size_t)(k0 + 16) * DH, Ks + 2048 + wave * 512);
    async16(VgT + k0, Vs + wave * 512);
    async16(VgT + (size_t)64 * SS + k0, Vs + 2048 + wave * 512);
    __syncthreads();
    if (k0 > qrow0 + 15) continue;  // wave-uniform; barriers already passed
    // S = Q K^T  (two 16-key halves)
    f32x4 s0 = {}, s1 = {};
#pragma unroll
    for (int c = 0; c < 4; c++) {
      short8 kf0 = *(const short8*)&Ks[(l16) * 128 + c * 32 + quad * 8];
      short8 kf1 = *(const short8*)&Ks[(16 + l16) * 128 + c * 32 + quad * 8];
      s0 = mfma16(qf[c], kf0, s0);
      s1 = mfma16(qf[c], kf1, s1);
    }
    float p0[4], p1[4], alpha[4];
#pragma unroll
    for (int r = 0; r < 4; r++) {
      const int qg = qrow0 + quad * 4 + r;
      float v0 = s0[r] * SCALE; if (k0 + l16 > qg) v0 = -1e4f;
      float v1 = s1[r] * SCALE; if (k0 + 16 + l16 > qg) v1 = -1e4f;
      p0[r] = v0; p1[r] = v1;
      float mx = fmaxf(v0, v1);
      mx = fmaxf(mx, __shfl_xor(mx, 1, 64));
      mx = fmaxf(mx, __shfl_xor(mx, 2, 64));
      mx = fmaxf(mx, __shfl_xor(mx, 4, 64));
      mx = fmaxf(mx, __shfl_xor(mx, 8, 64));
      float mn = fmaxf(m_i[r], mx);
      alpha[r] = __expf(m_i[r] - mn);
      m_i[r] = mn;
      float e0 = __expf(p0[r] - mn), e1 = __expf(p1[r] - mn);
      float rs = e0 + e1;
      rs += __shfl_xor(rs, 1, 64);
      rs += __shfl_xor(rs, 2, 64);
      rs += __shfl_xor(rs, 4, 64);
      rs += __shfl_xor(rs, 8, 64);
      l_i[r] = l_i[r] * alpha[r] + rs;
      Ps[wave][(quad * 4 + r) * 32 + l16] = f2bf(e0);
      Ps[wave][(quad * 4 + r) * 32 + 16 + l16] = f2bf(e1);
    }
    // O rescale
#pragma unroll
    for (int f = 0; f < 8; f++)
#pragma unroll
      for (int r = 0; r < 4; r++) o[f][r] *= alpha[r];
    // P: C-layout -> A-layout via per-wave LDS; same-wave, so lgkmcnt drain suffices
    asm volatile("s_waitcnt lgkmcnt(0)" ::: "memory");
    short8 pf = *(const short8*)&Ps[wave][l16 * 32 + quad * 8];
#pragma unroll
    for (int f = 0; f < 8; f++) {
      short8 vf = *(const short8*)&Vs[(f * 16 + l16) * 32 + quad * 8];
      o[f] = mfma16(pf, vf, o[f]);
    }
  }
  float invl[4];
#pragma unroll
  for (int r = 0; r < 4; r++) invl[r] = 1.f / l_i[r];
  unsigned short* Op = O + ((size_t)(b * SS + qrow0 + quad * 4)) * DD + h * DH + l16;
#pragma unroll
  for (int r = 0; r < 4; r++)
#pragma unroll
    for (int f = 0; f < 8; f++)
      Op[(size_t)r * DD + f * 16] = f2bf(o[f][r] * invl[r]);
}

// -------------------------------------------------------------------------------
extern "C" void kernel_launch(void* const* d_in, const int* in_sizes, int n_in,
                              void* d_out, int out_size, void* d_ws, size_t ws_size,
                              hipStream_t stream) {
  const float* hs      = (const float*)d_in[0];
  const float* wqkv    = (const float*)d_in[1];
  const float* wout    = (const float*)d_in[2];
  const float* q_scale = (const float*)d_in[3];
  const float* k_scale = (const float*)d_in[4];
  const float* cosc    = (const float*)d_in[5];
  const float* sinc    = (const float*)d_in[6];
  // d_in[7] = attention_mask: causal, recomputed from indices — not read.
  float* out = (float*)d_out;

  unsigned short* ws = (unsigned short*)d_ws;
  // live ranges allow aliasing: total 160 MiB
  unsigned short* wqkvT = ws;                        // 6144*4096 = 25165824
  unsigned short* woutT = wqkvT + 25165824;          // 4096*4096 = 16777216
  unsigned short* hsb   = woutT + 16777216;          // 4096*4096 = 16777216
  unsigned short* qkv   = hsb + 16777216;            // 4096*6144 = 25165824
  unsigned short* qrope = wqkvT;                     // alias (wqkvT dead after GEMM1)
  unsigned short* krope = wqkvT + 16777216;
  unsigned short* vT    = wqkvT + 16777216 + 4194304;
  unsigned short* attno = hsb;                       // alias (hsb dead after GEMM1)

  cast_bf16_kernel<<<16384, 256, 0, stream>>>(hs, hsb, 4194304);
  transpose_cast_kernel<<<dim3(192, 128), dim3(32, 8), 0, stream>>>(wqkv, wqkvT, 4096, 6144);
  transpose_cast_kernel<<<dim3(128, 128), dim3(32, 8), 0, stream>>>(wout, woutT, 4096, 4096);
  gemm_bt<unsigned short><<<dim3(32, 48), 256, 0, stream>>>(hsb, wqkvT, qkv, 4096, 6144, 4096);
  rmsnorm_rope_kernel<<<4096, 256, 0, stream>>>(qkv, q_scale, k_scale, cosc, sinc,
                                                qrope, krope, vT);
  flash_attn<<<dim3(32, 64), 256, 0, stream>>>(qrope, krope, vT, attno);
  gemm_bt<float><<<dim3(32, 32), 256, 0, stream>>>(attno, woutT, out, 4096, 4096, 4096);
}

// Round 2
// 837.166 us; speedup vs baseline: 1.4972x; 1.4972x over previous
//
#include <hip/hip_runtime.h>
#include <hip/hip_bf16.h>
#include <cstdint>
#include <cstddef>

// Problem constants
#define BB 2
#define SS 2048
#define DD 4096
#define HH 32
#define KVH 8
#define DH 128
#define KVD 1024
#define SCALE 0.08838834764831845f   // DH^-0.5
// SCALE * log2(e): folded into Q so softmax runs in exp2 domain
#define QSC 0.1275178745225f

typedef __attribute__((ext_vector_type(8))) short short8;
typedef __attribute__((ext_vector_type(4))) float f32x4;

typedef __attribute__((address_space(1))) void GV;
typedef __attribute__((address_space(3))) void LV;

__device__ __forceinline__ void async16(const void* g, void* l) {
  __builtin_amdgcn_global_load_lds((GV*)g, (LV*)l, 16, 0, 0);
}

__device__ __forceinline__ unsigned short f2bf(float x) {
  union { float f; uint32_t u; } v; v.f = x;
  uint32_t r = (v.u + 0x7fffu + ((v.u >> 16) & 1u)) >> 16;
  return (unsigned short)r;
}
__device__ __forceinline__ float bf2f(unsigned short b) {
  union { uint32_t u; float f; } v; v.u = ((uint32_t)b) << 16; return v.f;
}
__device__ __forceinline__ f32x4 mfma16(short8 a, short8 b, f32x4 c) {
  return __builtin_amdgcn_mfma_f32_16x16x32_bf16(a, b, c, 0, 0, 0);
}

// ---------------- cast fp32 -> bf16 (straight) ----------------
__global__ __launch_bounds__(256) void cast_bf16_kernel(
    const float* __restrict__ in, unsigned short* __restrict__ out, int n4) {
  int i = blockIdx.x * 256 + threadIdx.x;
  if (i >= n4) return;
  float4 v = ((const float4*)in)[i];
  ushort4 o;
  o.x = f2bf(v.x); o.y = f2bf(v.y); o.z = f2bf(v.z); o.w = f2bf(v.w);
  ((ushort4*)out)[i] = o;
}

// ---------------- cast + transpose: (R x C) fp32 -> (C x R) bf16 ----------------
__global__ __launch_bounds__(256) void transpose_cast_kernel(
    const float* __restrict__ in, unsigned short* __restrict__ out, int R, int C) {
  __shared__ unsigned short tile[32][33];
  const int tx = threadIdx.x, ty = threadIdx.y;       // block (32,8)
  const int c0 = blockIdx.x * 32, r0 = blockIdx.y * 32;
  for (int i = ty; i < 32; i += 8)
    tile[i][tx] = f2bf(in[(size_t)(r0 + i) * C + c0 + tx]);
  __syncthreads();
  for (int i = ty; i < 32; i += 8)
    out[(size_t)(c0 + i) * R + r0 + tx] = tile[tx][i];
}

// ---------------- GEMM: C[M,N] = A[M,K] * Bt[N,K]^T  (bf16 in, fp32 acc) ----------
template <typename OutT>
__global__ __launch_bounds__(256, 2) void gemm_bt(
    const unsigned short* __restrict__ A, const unsigned short* __restrict__ Bt,
    OutT* __restrict__ C, int M, int N, int K) {
  __shared__ __align__(16) unsigned short As[4096];  // [128][32]
  __shared__ __align__(16) unsigned short Bs[4096];  // [128][32]
  const int tid = threadIdx.x;
  const int wave = tid >> 6, lane = tid & 63, quad = lane >> 4, l16 = lane & 15;
  const int m0 = blockIdx.x * 128, n0 = blockIdx.y * 128;
  const int wm = (wave & 1) * 64, wn = (wave >> 1) * 64;
  f32x4 acc[4][4] = {};
  const int sr = tid >> 2, sc = (tid & 3) * 8;
  const unsigned short* Ag = A + (size_t)(m0 + sr) * K + sc;
  const unsigned short* Bg = Bt + (size_t)(n0 + sr) * K + sc;
  unsigned short* AsW = As + wave * 512;
  unsigned short* BsW = Bs + wave * 512;
  for (int k0 = 0; k0 < K; k0 += 32) {
    __syncthreads();
    async16(Ag + k0, AsW);
    async16(Ag + (size_t)64 * K + k0, AsW + 2048);
    async16(Bg + k0, BsW);
    async16(Bg + (size_t)64 * K + k0, BsW + 2048);
    __syncthreads();
    short8 af[4], bf[4];
#pragma unroll
    for (int i = 0; i < 4; i++) {
      af[i] = *(const short8*)&As[(wm + i * 16 + l16) * 32 + quad * 8];
      bf[i] = *(const short8*)&Bs[(wn + i * 16 + l16) * 32 + quad * 8];
    }
#pragma unroll
    for (int mi = 0; mi < 4; mi++)
#pragma unroll
      for (int ni = 0; ni < 4; ni++)
        acc[mi][ni] = mfma16(af[mi], bf[ni], acc[mi][ni]);
  }
#pragma unroll
  for (int mi = 0; mi < 4; mi++)
#pragma unroll
    for (int ni = 0; ni < 4; ni++)
#pragma unroll
      for (int r = 0; r < 4; r++) {
        int row = m0 + wm + mi * 16 + quad * 4 + r;
        int col = n0 + wn + ni * 16 + l16;
        float v = acc[mi][ni][r];
        if constexpr (sizeof(OutT) == 4) C[(size_t)row * N + col] = v;
        else                             C[(size_t)row * N + col] = (OutT)f2bf(v);
      }
}

// ---------------- RMSNorm + RoPE + V transpose --------
// Q output is pre-scaled by QSC = SCALE*log2(e) so attention softmax runs in exp2 domain.
__global__ __launch_bounds__(256) void rmsnorm_rope_kernel(
    const unsigned short* __restrict__ qkv,
    const float* __restrict__ q_scale, const float* __restrict__ k_scale,
    const float* __restrict__ cosc, const float* __restrict__ sinc,
    unsigned short* __restrict__ qo,   // (B,H,S,DH)
    unsigned short* __restrict__ ko,   // (B,KVH,S,DH)
    unsigned short* __restrict__ vo)   // (B,KVH,DH,S)  transposed
{
  const int row = blockIdx.x;              // b*S + s
  const int b = row >> 11, s = row & 2047;
  const int tid = threadIdx.x;
  const unsigned short* qr = qkv + (size_t)row * 6144;
  float sq = 0.f, sk = 0.f;
  for (int c = tid; c < 4096; c += 256) { float v = bf2f(qr[c]); sq += v * v; }
  for (int c = tid; c < 1024; c += 256) { float v = bf2f(qr[4096 + c]); sk += v * v; }
#pragma unroll
  for (int off = 32; off; off >>= 1) {
    sq += __shfl_down(sq, off, 64);
    sk += __shfl_down(sk, off, 64);
  }
  __shared__ float redq[4], redk[4];
  if ((tid & 63) == 0) { redq[tid >> 6] = sq; redk[tid >> 6] = sk; }
  __syncthreads();
  sq = redq[0] + redq[1] + redq[2] + redq[3];
  sk = redk[0] + redk[1] + redk[2] + redk[3];
  const float rq = rsqrtf(sq * (1.f / 4096.f) + 1e-6f);
  const float rk = rsqrtf(sk * (1.f / 1024.f) + 1e-6f);
  const float* cp = cosc + (size_t)row * 128;
  const float* sp = sinc + (size_t)row * 128;
  for (int c = tid; c < 4096; c += 256) {
    int d = c & 127, hh = c >> 7;
    float v = bf2f(qr[c]) * rq * q_scale[c];
    int c2 = (d < 64) ? c + 64 : c - 64;
    float v2 = bf2f(qr[c2]) * rq * q_scale[c2];
    float rot = (d < 64) ? -v2 : v2;
    qo[((size_t)(b * HH + hh) * SS + s) * DH + d] = f2bf((v * cp[d] + rot * sp[d]) * QSC);
  }
  for (int c = tid; c < 1024; c += 256) {
    int d = c & 127, hh = c >> 7;
    float v = bf2f(qr[4096 + c]) * rk * k_scale[c];
    int kc2 = (d < 64) ? c + 64 : c - 64;
    float v2 = bf2f(qr[4096 + kc2]) * rk * k_scale[kc2];
    float rot = (d < 64) ? -v2 : v2;
    ko[((size_t)(b * KVH + hh) * SS + s) * DH + d] = f2bf(v * cp[d] + rot * sp[d]);
  }
  for (int c = tid; c < 1024; c += 256) {
    int d = c & 127, hh = c >> 7;
    vo[((size_t)(b * KVH + hh) * DH + d) * SS + s] = qr[5120 + c];
  }
}

// ---------------- Flash attention v2: S^T form, 128 q-rows/block, 64-key tiles -----
// grid (B*H, S/128); wave w owns q-rows qbase + {w*16..w*16+15} and +64.
// All LDS tiles XOR-swizzled in 16B granules -> 2-way max on b128 reads (free).
__global__ __launch_bounds__(256, 2) void flash_attn(
    const unsigned short* __restrict__ Q,   // (B,H,S,DH), pre-scaled by QSC
    const unsigned short* __restrict__ Kr,  // (B,KVH,S,DH)
    const unsigned short* __restrict__ Vt,  // (B,KVH,DH,S)
    unsigned short* __restrict__ O)         // (B,S,H*DH)
{
  __shared__ __align__(16) unsigned short Ks[8192];   // 64 keys x 128 d (swizzled)
  __shared__ __align__(16) unsigned short Vs[8192];   // 128 d x 64 keys (swizzled)
  __shared__ __align__(16) unsigned int   Ps[4][1024];// per-wave P [32 m][64 k] bf16 (swizzled)
  const int tid = threadIdx.x, wave = tid >> 6, lane = tid & 63;
  const int quad = lane >> 4, l16 = lane & 15;
  const int bh = blockIdx.x, b = bh >> 5, h = bh & 31;
  const int kvh = h >> 2;
  const int qbase = ((int)gridDim.y - 1 - (int)blockIdx.y) * 128;  // heavy-first
  const unsigned short* Qb = Q + (size_t)(b * HH + h) * SS * DH;
  short8 qf[2][4];
#pragma unroll
  for (int mi = 0; mi < 2; mi++) {
    const unsigned short* Qp = Qb + (size_t)(qbase + mi * 64 + wave * 16 + l16) * DH + quad * 8;
#pragma unroll
    for (int c = 0; c < 4; c++) qf[mi][c] = *(const short8*)(Qp + c * 32);
  }
  const unsigned short* Kg = Kr + (size_t)(b * KVH + kvh) * SS * DH;
  const unsigned short* Vg = Vt + (size_t)(b * KVH + kvh) * DH * SS;
  // staging source offsets (swizzle applied on the GLOBAL side; LDS dst is lane-pinned)
  int bK[4], bV[4];
#pragma unroll
  for (int j = 0; j < 4; j++) {
    const int kk = wave * 16 + j * 4 + quad;                 // key row in tile
    const int gd = l16 ^ ((j * 4 + quad) & 15);              // d-granule fetched
    bK[j] = kk * 128 + gd * 8;
    const int dd = (wave * 4 + j) * 8 + (lane >> 3);         // d row
    const int gk = (lane & 7) ^ ((lane >> 3) & 7);           // key-granule fetched
    bV[j] = dd * 2048 + gk * 8;
  }
  f32x4 o[2][8] = {};
  float m_i[2] = {-1e30f, -1e30f}, l_i[2] = {0.f, 0.f};
  const int ndiag = qbase >> 6;
  const int nkt = ndiag + 2;
  for (int kt = 0; kt < nkt; kt++) {
    const int k0 = kt * 64;
    __syncthreads();
#pragma unroll
    for (int j = 0; j < 4; j++) {
      async16(Kg + (size_t)k0 * 128 + bK[j], Ks + (wave * 4 + j) * 512);
      async16(Vg + k0 + bV[j], Vs + (wave * 4 + j) * 512);
    }
    __syncthreads();
    // S^T = K_tile * Q_w^T : C[m=key][n=qrow]
    f32x4 st[4][2] = {};
#pragma unroll
    for (int km = 0; km < 4; km++) {
      const unsigned short* krow = Ks + (km * 16 + l16) * 128;
#pragma unroll
      for (int c = 0; c < 4; c++) {
        short8 kf = *(const short8*)(krow + (((c * 4 + quad) ^ l16) * 8));
        st[km][0] = mfma16(kf, qf[0][c], st[km][0]);
        st[km][1] = mfma16(kf, qf[1][c], st[km][1]);
      }
    }
    const bool mtile = (kt >= ndiag);
    float alpha[2];
#pragma unroll
    for (int mi = 0; mi < 2; mi++) {
      if (mtile) {
        const int qg = qbase + mi * 64 + wave * 16 + l16;
#pragma unroll
        for (int km = 0; km < 4; km++)
#pragma unroll
          for (int r = 0; r < 4; r++)
            if (k0 + km * 16 + quad * 4 + r > qg) st[km][mi][r] = -1e4f;
      }
      float tmax = -3e38f;
#pragma unroll
      for (int km = 0; km < 4; km++)
#pragma unroll
        for (int r = 0; r < 4; r++) tmax = fmaxf(tmax, st[km][mi][r]);
      tmax = fmaxf(tmax, __shfl_xor(tmax, 16, 64));
      tmax = fmaxf(tmax, __shfl_xor(tmax, 32, 64));
      const float mn = fmaxf(m_i[mi], tmax);
      alpha[mi] = __builtin_amdgcn_exp2f(m_i[mi] - mn);
      m_i[mi] = mn;
      float rs = 0.f;
#pragma unroll
      for (int km = 0; km < 4; km++)
#pragma unroll
        for (int r = 0; r < 4; r++) {
          float e = __builtin_amdgcn_exp2f(st[km][mi][r] - mn);
          st[km][mi][r] = e;
          rs += e;
        }
      rs += __shfl_xor(rs, 16, 64);
      rs += __shfl_xor(rs, 32, 64);
      l_i[mi] = l_i[mi] * alpha[mi] + rs;
      // pack P^T -> Ps[m][key] (bf16, truncating v_perm pack), swizzled
      unsigned int* pw = &Ps[wave][(mi * 16 + l16) * 32 + (quad & 1) * 2];
#pragma unroll
      for (int km = 0; km < 4; km++) {
        const int g = (km * 2 + (quad >> 1)) ^ (l16 & 7);
        float e0 = st[km][mi][0], e1 = st[km][mi][1], e2 = st[km][mi][2], e3 = st[km][mi][3];
        pw[g * 4]     = __builtin_amdgcn_perm(__builtin_bit_cast(unsigned int, e1),
                                              __builtin_bit_cast(unsigned int, e0), 0x07060302u);
        pw[g * 4 + 1] = __builtin_amdgcn_perm(__builtin_bit_cast(unsigned int, e3),
                                              __builtin_bit_cast(unsigned int, e2), 0x07060302u);
      }
    }
    // O rescale only when a new max appeared anywhere in the wave.
    // alpha is per-l16(row); O rows live at quad*4+r -> transpose via shfl.
    if (__any((alpha[0] != 1.f) || (alpha[1] != 1.f))) {
#pragma unroll
      for (int mi = 0; mi < 2; mi++) {
        float ar[4];
#pragma unroll
        for (int r = 0; r < 4; r++)
          ar[r] = __shfl(alpha[mi], (lane & 48) + quad * 4 + r, 64);
#pragma unroll
        for (int f = 0; f < 8; f++)
#pragma unroll
          for (int r = 0; r < 4; r++) o[mi][f][r] *= ar[r];
      }
    }
    // O += P * V^T
#pragma unroll
    for (int kc = 0; kc < 2; kc++) {
      short8 pa[2];
#pragma unroll
      for (int mi = 0; mi < 2; mi++) {
        const int g = (kc * 4 + quad) ^ (l16 & 7);
        uint4 pv4 = *(const uint4*)&Ps[wave][(mi * 16 + l16) * 32 + g * 4];
        pa[mi] = __builtin_bit_cast(short8, pv4);
      }
#pragma unroll
      for (int f = 0; f < 8; f++) {
        const int d = f * 16 + l16;
        short8 vf = *(const short8*)(Vs + d * 64 + (((kc * 4 + quad) ^ (l16 & 7)) * 8));
        o[0][f] = mfma16(pa[0], vf, o[0][f]);
        o[1][f] = mfma16(pa[1], vf, o[1][f]);
      }
    }
  }
  // epilogue: l_i is per-l16(row); O rows at quad*4+r -> transpose via shfl
  float il[2][4];
#pragma unroll
  for (int mi = 0; mi < 2; mi++)
#pragma unroll
    for (int r = 0; r < 4; r++) {
      float lv = __shfl(l_i[mi], (lane & 48) + quad * 4 + r, 64);
      il[mi][r] = 1.f / lv;
    }
#pragma unroll
  for (int mi = 0; mi < 2; mi++) {
    unsigned short* Op = O + (size_t)(b * SS + qbase + mi * 64 + wave * 16 + quad * 4) * DD + h * DH + l16;
#pragma unroll
    for (int f = 0; f < 8; f++)
#pragma unroll
      for (int r = 0; r < 4; r++)
        Op[(size_t)r * DD + f * 16] = f2bf(o[mi][f][r] * il[mi][r]);
  }
}

// -------------------------------------------------------------------------------
extern "C" void kernel_launch(void* const* d_in, const int* in_sizes, int n_in,
                              void* d_out, int out_size, void* d_ws, size_t ws_size,
                              hipStream_t stream) {
  const float* hs      = (const float*)d_in[0];
  const float* wqkv    = (const float*)d_in[1];
  const float* wout    = (const float*)d_in[2];
  const float* q_scale = (const float*)d_in[3];
  const float* k_scale = (const float*)d_in[4];
  const float* cosc    = (const float*)d_in[5];
  const float* sinc    = (const float*)d_in[6];
  // d_in[7] = attention_mask: causal, recomputed from indices — not read.
  float* out = (float*)d_out;

  unsigned short* ws = (unsigned short*)d_ws;
  unsigned short* wqkvT = ws;                        // 6144*4096 = 25165824
  unsigned short* woutT = wqkvT + 25165824;          // 4096*4096 = 16777216
  unsigned short* hsb   = woutT + 16777216;          // 4096*4096 = 16777216
  unsigned short* qkv   = hsb + 16777216;            // 4096*6144 = 25165824
  unsigned short* qrope = wqkvT;                     // alias (wqkvT dead after GEMM1)
  unsigned short* krope = wqkvT + 16777216;
  unsigned short* vT    = wqkvT + 16777216 + 4194304;
  unsigned short* attno = hsb;                       // alias (hsb dead after GEMM1)

  cast_bf16_kernel<<<16384, 256, 0, stream>>>(hs, hsb, 4194304);
  transpose_cast_kernel<<<dim3(192, 128), dim3(32, 8), 0, stream>>>(wqkv, wqkvT, 4096, 6144);
  transpose_cast_kernel<<<dim3(128, 128), dim3(32, 8), 0, stream>>>(wout, woutT, 4096, 4096);
  gemm_bt<unsigned short><<<dim3(32, 48), 256, 0, stream>>>(hsb, wqkvT, qkv, 4096, 6144, 4096);
  rmsnorm_rope_kernel<<<4096, 256, 0, stream>>>(qkv, q_scale, k_scale, cosc, sinc,
                                                qrope, krope, vT);
  flash_attn<<<dim3(64, 16), 256, 0, stream>>>(qrope, krope, vT, attno);
  gemm_bt<float><<<dim3(32, 32), 256, 0, stream>>>(attno, woutT, out, 4096, 4096, 4096);
}

// Round 3
// 799.604 us; speedup vs baseline: 1.5675x; 1.0470x over previous
//
#include <hip/hip_runtime.h>
#include <hip/hip_bf16.h>
#include <cstdint>
#include <cstddef>

// Problem constants
#define BB 2
#define SS 2048
#define DD 4096
#define HH 32
#define KVH 8
#define DH 128
#define KVD 1024
#define SCALE 0.08838834764831845f   // DH^-0.5
// SCALE * log2(e): folded into Q so softmax runs in exp2 domain
#define QSC 0.1275178745225f

typedef __attribute__((ext_vector_type(8))) short short8;
typedef __attribute__((ext_vector_type(4))) float f32x4;

typedef __attribute__((address_space(1))) void GV;
typedef __attribute__((address_space(3))) void LV;

__device__ __forceinline__ void async16(const void* g, void* l) {
  __builtin_amdgcn_global_load_lds((GV*)g, (LV*)l, 16, 0, 0);
}

__device__ __forceinline__ unsigned short f2bf(float x) {
  union { float f; uint32_t u; } v; v.f = x;
  uint32_t r = (v.u + 0x7fffu + ((v.u >> 16) & 1u)) >> 16;
  return (unsigned short)r;
}
__device__ __forceinline__ float bf2f(unsigned short b) {
  union { uint32_t u; float f; } v; v.u = ((uint32_t)b) << 16; return v.f;
}
__device__ __forceinline__ f32x4 mfma16(short8 a, short8 b, f32x4 c) {
  return __builtin_amdgcn_mfma_f32_16x16x32_bf16(a, b, c, 0, 0, 0);
}

// ---------------- cast fp32 -> bf16 (straight) ----------------
__global__ __launch_bounds__(256) void cast_bf16_kernel(
    const float* __restrict__ in, unsigned short* __restrict__ out, int n4) {
  int i = blockIdx.x * 256 + threadIdx.x;
  if (i >= n4) return;
  float4 v = ((const float4*)in)[i];
  ushort4 o;
  o.x = f2bf(v.x); o.y = f2bf(v.y); o.z = f2bf(v.z); o.w = f2bf(v.w);
  ((ushort4*)out)[i] = o;
}

// ---------------- cast + transpose: (R x C) fp32 -> (C x R) bf16 ----------------
__global__ __launch_bounds__(256) void transpose_cast_kernel(
    const float* __restrict__ in, unsigned short* __restrict__ out, int R, int C) {
  __shared__ unsigned short tile[32][33];
  const int tx = threadIdx.x, ty = threadIdx.y;       // block (32,8)
  const int c0 = blockIdx.x * 32, r0 = blockIdx.y * 32;
  for (int i = ty; i < 32; i += 8)
    tile[i][tx] = f2bf(in[(size_t)(r0 + i) * C + c0 + tx]);
  __syncthreads();
  for (int i = ty; i < 32; i += 8)
    out[(size_t)(c0 + i) * R + r0 + tx] = tile[tx][i];
}

// ---------------- V transpose: qkv[b*S+s][5120 + kvh*128 + d] -> vo[(b,kvh,d,s)] ----
__global__ __launch_bounds__(256) void transpose_v_kernel(
    const unsigned short* __restrict__ qkv, unsigned short* __restrict__ vo) {
  __shared__ unsigned short tile[32][33];
  const int s0 = blockIdx.x * 32, d0 = blockIdx.y * 32;
  const int b = blockIdx.z >> 3, kvh = blockIdx.z & 7;
  const int tx = threadIdx.x, ty = threadIdx.y;       // block (32,8)
  const unsigned short* ip = qkv + 5120 + (size_t)kvh * 128 + d0 + tx;
  for (int i = ty; i < 32; i += 8)
    tile[i][tx] = ip[(size_t)(b * SS + s0 + i) * 6144];
  __syncthreads();
  unsigned short* op = vo + (size_t)(b * KVH + kvh) * DH * SS + s0 + tx;
  for (int i = ty; i < 32; i += 8)
    op[(size_t)(d0 + i) * SS] = tile[tx][i];
}

// ---------------- GEMM: C[M,N] = A[M,K] * Bt[N,K]^T  (bf16 in, fp32 acc) ----------
// m97 structure + XOR bank-swizzle: granule g of tile-row r lives at physical
// granule g ^ ((r>>1)&3). Swizzle applied on the GLOBAL fetch side (LDS dst of
// global_load_lds is lane-pinned). ds_read_b128 bank-group becomes
// 4*(r&1) + (quad ^ ((r>>1)&3)) -> all 8 groups, 2 lanes each = conflict-free.
template <typename OutT>
__global__ __launch_bounds__(256, 2) void gemm_bt(
    const unsigned short* __restrict__ A, const unsigned short* __restrict__ Bt,
    OutT* __restrict__ C, int M, int N, int K) {
  __shared__ __align__(16) unsigned short As[4096];  // [128][32] swizzled
  __shared__ __align__(16) unsigned short Bs[4096];  // [128][32] swizzled
  const int tid = threadIdx.x;
  const int wave = tid >> 6, lane = tid & 63, quad = lane >> 4, l16 = lane & 15;
  const int m0 = blockIdx.x * 128, n0 = blockIdx.y * 128;
  const int wm = (wave & 1) * 64, wn = (wave >> 1) * 64;
  f32x4 acc[4][4] = {};
  // staging: lane covers tile-row sr (0..63 within half), physical granule tid&3;
  // fetch logical granule sg = (tid&3) ^ ((sr>>1)&3) = (tid&3) ^ ((tid>>3)&3)
  const int sr = tid >> 2;
  const int sg = (tid & 3) ^ ((tid >> 3) & 3);
  const unsigned short* Ag = A + (size_t)(m0 + sr) * K + sg * 8;
  const unsigned short* Bg = Bt + (size_t)(n0 + sr) * K + sg * 8;
  unsigned short* AsW = As + wave * 512;
  unsigned short* BsW = Bs + wave * 512;
  // fragment-read physical granule: quad ^ ((r>>1)&3), r = wm+i*16+l16 -> l16 only
  const int pg = (quad ^ ((l16 >> 1) & 3)) * 8;
  for (int k0 = 0; k0 < K; k0 += 32) {
    __syncthreads();
    async16(Ag + k0, AsW);
    async16(Ag + (size_t)64 * K + k0, AsW + 2048);
    async16(Bg + k0, BsW);
    async16(Bg + (size_t)64 * K + k0, BsW + 2048);
    __syncthreads();
    short8 af[4], bf[4];
#pragma unroll
    for (int i = 0; i < 4; i++) {
      af[i] = *(const short8*)&As[(wm + i * 16 + l16) * 32 + pg];
      bf[i] = *(const short8*)&Bs[(wn + i * 16 + l16) * 32 + pg];
    }
#pragma unroll
    for (int mi = 0; mi < 4; mi++)
#pragma unroll
      for (int ni = 0; ni < 4; ni++)
        acc[mi][ni] = mfma16(af[mi], bf[ni], acc[mi][ni]);
  }
#pragma unroll
  for (int mi = 0; mi < 4; mi++)
#pragma unroll
    for (int ni = 0; ni < 4; ni++)
#pragma unroll
      for (int r = 0; r < 4; r++) {
        int row = m0 + wm + mi * 16 + quad * 4 + r;
        int col = n0 + wn + ni * 16 + l16;
        float v = acc[mi][ni][r];
        if constexpr (sizeof(OutT) == 4) C[(size_t)row * N + col] = v;
        else                             C[(size_t)row * N + col] = (OutT)f2bf(v);
      }
}

// ---------------- RMSNorm + RoPE (Q,K only; V handled by transpose_v) --------
// Q output pre-scaled by QSC = SCALE*log2(e) so softmax runs in exp2 domain.
__global__ __launch_bounds__(256) void rmsnorm_rope_kernel(
    const unsigned short* __restrict__ qkv,
    const float* __restrict__ q_scale, const float* __restrict__ k_scale,
    const float* __restrict__ cosc, const float* __restrict__ sinc,
    unsigned short* __restrict__ qo,   // (B,H,S,DH)
    unsigned short* __restrict__ ko)   // (B,KVH,S,DH)
{
  const int row = blockIdx.x;              // b*S + s
  const int b = row >> 11, s = row & 2047;
  const int tid = threadIdx.x;
  const unsigned short* qr = qkv + (size_t)row * 6144;
  // vectorized sum of squares
  short8 qv0 = *(const short8*)&qr[tid * 8];
  short8 qv1 = *(const short8*)&qr[2048 + tid * 8];
  ushort4 kv = *(const ushort4*)&qr[4096 + tid * 4];
  float sq = 0.f, sk = 0.f;
#pragma unroll
  for (int e = 0; e < 8; e++) {
    float a = bf2f((unsigned short)qv0[e]); sq += a * a;
    float c = bf2f((unsigned short)qv1[e]); sq += c * c;
  }
  float kf[4];
#pragma unroll
  for (int e = 0; e < 4; e++) {
    kf[e] = bf2f(((const unsigned short*)&kv)[e]); sk += kf[e] * kf[e];
  }
#pragma unroll
  for (int off = 32; off; off >>= 1) {
    sq += __shfl_down(sq, off, 64);
    sk += __shfl_down(sk, off, 64);
  }
  __shared__ float redq[4], redk[4];
  if ((tid & 63) == 0) { redq[tid >> 6] = sq; redk[tid >> 6] = sk; }
  __syncthreads();
  sq = redq[0] + redq[1] + redq[2] + redq[3];
  sk = redk[0] + redk[1] + redk[2] + redk[3];
  const float rq = rsqrtf(sq * (1.f / 4096.f) + 1e-6f);
  const float rk = rsqrtf(sk * (1.f / 1024.f) + 1e-6f);
  const float* cp = cosc + (size_t)row * 128;
  const float* sp = sinc + (size_t)row * 128;
  // Q: two chunks of 8 contiguous elems per thread
#pragma unroll
  for (int it = 0; it < 2; it++) {
    const int c = it * 2048 + tid * 8;
    const int d = c & 127, hh = c >> 7;
    short8 v8 = it ? qv1 : qv0;
    short8 p8 = *(const short8*)&qr[c ^ 64];   // rotate-half partner granule
    const float sgn = (d < 64) ? -1.f : 1.f;
    ushort o8[8];
#pragma unroll
    for (int e = 0; e < 8; e++) {
      float v = bf2f((unsigned short)v8[e]) * rq * q_scale[c + e];
      float p = bf2f((unsigned short)p8[e]) * rq * q_scale[(c ^ 64) + e];
      o8[e] = f2bf((v * cp[d + e] + sgn * p * sp[d + e]) * QSC);
    }
    *(uint4*)&qo[((size_t)(b * HH + hh) * SS + s) * DH + d] = *(const uint4*)o8;
  }
  // K: 4 contiguous elems per thread
  {
    const int c = tid * 4;
    const int d = c & 127, hh = c >> 7;
    ushort4 p4 = *(const ushort4*)&qr[4096 + (c ^ 64)];
    const float sgn = (d < 64) ? -1.f : 1.f;
    ushort o4[4];
#pragma unroll
    for (int e = 0; e < 4; e++) {
      float v = kf[e] * rk * k_scale[c + e];
      float p = bf2f(((const unsigned short*)&p4)[e]) * rk * k_scale[(c ^ 64) + e];
      o4[e] = f2bf(v * cp[d + e] + sgn * p * sp[d + e]);
    }
    *(uint2*)&ko[((size_t)(b * KVH + hh) * SS + s) * DH + d] = *(const uint2*)o4;
  }
}

// ---------------- Flash attention: S^T form, 128 q-rows/block, 64-key tiles -----
__global__ __launch_bounds__(256, 2) void flash_attn(
    const unsigned short* __restrict__ Q,   // (B,H,S,DH), pre-scaled by QSC
    const unsigned short* __restrict__ Kr,  // (B,KVH,S,DH)
    const unsigned short* __restrict__ Vt,  // (B,KVH,DH,S)
    unsigned short* __restrict__ O)         // (B,S,H*DH)
{
  __shared__ __align__(16) unsigned short Ks[8192];   // 64 keys x 128 d (swizzled)
  __shared__ __align__(16) unsigned short Vs[8192];   // 128 d x 64 keys (swizzled)
  __shared__ __align__(16) unsigned int   Ps[4][1024];// per-wave P [32 m][64 k] bf16 (swizzled)
  const int tid = threadIdx.x, wave = tid >> 6, lane = tid & 63;
  const int quad = lane >> 4, l16 = lane & 15;
  const int bh = blockIdx.x, b = bh >> 5, h = bh & 31;
  const int kvh = h >> 2;
  const int qbase = ((int)gridDim.y - 1 - (int)blockIdx.y) * 128;  // heavy-first
  const unsigned short* Qb = Q + (size_t)(b * HH + h) * SS * DH;
  short8 qf[2][4];
#pragma unroll
  for (int mi = 0; mi < 2; mi++) {
    const unsigned short* Qp = Qb + (size_t)(qbase + mi * 64 + wave * 16 + l16) * DH + quad * 8;
#pragma unroll
    for (int c = 0; c < 4; c++) qf[mi][c] = *(const short8*)(Qp + c * 32);
  }
  const unsigned short* Kg = Kr + (size_t)(b * KVH + kvh) * SS * DH;
  const unsigned short* Vg = Vt + (size_t)(b * KVH + kvh) * DH * SS;
  int bK[4], bV[4];
#pragma unroll
  for (int j = 0; j < 4; j++) {
    const int kk = wave * 16 + j * 4 + quad;
    const int gd = l16 ^ ((j * 4 + quad) & 15);
    bK[j] = kk * 128 + gd * 8;
    const int dd = (wave * 4 + j) * 8 + (lane >> 3);
    const int gk = (lane & 7) ^ ((lane >> 3) & 7);
    bV[j] = dd * 2048 + gk * 8;
  }
  f32x4 o[2][8] = {};
  float m_i[2] = {-1e30f, -1e30f}, l_i[2] = {0.f, 0.f};
  const int ndiag = qbase >> 6;
  const int nkt = ndiag + 2;
  for (int kt = 0; kt < nkt; kt++) {
    const int k0 = kt * 64;
    __syncthreads();
#pragma unroll
    for (int j = 0; j < 4; j++) {
      async16(Kg + (size_t)k0 * 128 + bK[j], Ks + (wave * 4 + j) * 512);
      async16(Vg + k0 + bV[j], Vs + (wave * 4 + j) * 512);
    }
    __syncthreads();
    f32x4 st[4][2] = {};
#pragma unroll
    for (int km = 0; km < 4; km++) {
      const unsigned short* krow = Ks + (km * 16 + l16) * 128;
#pragma unroll
      for (int c = 0; c < 4; c++) {
        short8 kf = *(const short8*)(krow + (((c * 4 + quad) ^ l16) * 8));
        st[km][0] = mfma16(kf, qf[0][c], st[km][0]);
        st[km][1] = mfma16(kf, qf[1][c], st[km][1]);
      }
    }
    const bool mtile = (kt >= ndiag);
    float alpha[2];
#pragma unroll
    for (int mi = 0; mi < 2; mi++) {
      if (mtile) {
        const int qg = qbase + mi * 64 + wave * 16 + l16;
#pragma unroll
        for (int km = 0; km < 4; km++)
#pragma unroll
          for (int r = 0; r < 4; r++)
            if (k0 + km * 16 + quad * 4 + r > qg) st[km][mi][r] = -1e4f;
      }
      float tmax = -3e38f;
#pragma unroll
      for (int km = 0; km < 4; km++)
#pragma unroll
        for (int r = 0; r < 4; r++) tmax = fmaxf(tmax, st[km][mi][r]);
      tmax = fmaxf(tmax, __shfl_xor(tmax, 16, 64));
      tmax = fmaxf(tmax, __shfl_xor(tmax, 32, 64));
      const float mn = fmaxf(m_i[mi], tmax);
      alpha[mi] = __builtin_amdgcn_exp2f(m_i[mi] - mn);
      m_i[mi] = mn;
      float rs = 0.f;
#pragma unroll
      for (int km = 0; km < 4; km++)
#pragma unroll
        for (int r = 0; r < 4; r++) {
          float e = __builtin_amdgcn_exp2f(st[km][mi][r] - mn);
          st[km][mi][r] = e;
          rs += e;
        }
      rs += __shfl_xor(rs, 16, 64);
      rs += __shfl_xor(rs, 32, 64);
      l_i[mi] = l_i[mi] * alpha[mi] + rs;
      unsigned int* pw = &Ps[wave][(mi * 16 + l16) * 32 + (quad & 1) * 2];
#pragma unroll
      for (int km = 0; km < 4; km++) {
        const int g = (km * 2 + (quad >> 1)) ^ (l16 & 7);
        float e0 = st[km][mi][0], e1 = st[km][mi][1], e2 = st[km][mi][2], e3 = st[km][mi][3];
        pw[g * 4]     = __builtin_amdgcn_perm(__builtin_bit_cast(unsigned int, e1),
                                              __builtin_bit_cast(unsigned int, e0), 0x07060302u);
        pw[g * 4 + 1] = __builtin_amdgcn_perm(__builtin_bit_cast(unsigned int, e3),
                                              __builtin_bit_cast(unsigned int, e2), 0x07060302u);
      }
    }
    if (__any((alpha[0] != 1.f) || (alpha[1] != 1.f))) {
#pragma unroll
      for (int mi = 0; mi < 2; mi++) {
        float ar[4];
#pragma unroll
        for (int r = 0; r < 4; r++)
          ar[r] = __shfl(alpha[mi], (lane & 48) + quad * 4 + r, 64);
#pragma unroll
        for (int f = 0; f < 8; f++)
#pragma unroll
          for (int r = 0; r < 4; r++) o[mi][f][r] *= ar[r];
      }
    }
#pragma unroll
    for (int kc = 0; kc < 2; kc++) {
      short8 pa[2];
#pragma unroll
      for (int mi = 0; mi < 2; mi++) {
        const int g = (kc * 4 + quad) ^ (l16 & 7);
        uint4 pv4 = *(const uint4*)&Ps[wave][(mi * 16 + l16) * 32 + g * 4];
        pa[mi] = __builtin_bit_cast(short8, pv4);
      }
#pragma unroll
      for (int f = 0; f < 8; f++) {
        const int d = f * 16 + l16;
        short8 vf = *(const short8*)(Vs + d * 64 + (((kc * 4 + quad) ^ (l16 & 7)) * 8));
        o[0][f] = mfma16(pa[0], vf, o[0][f]);
        o[1][f] = mfma16(pa[1], vf, o[1][f]);
      }
    }
  }
  float il[2][4];
#pragma unroll
  for (int mi = 0; mi < 2; mi++)
#pragma unroll
    for (int r = 0; r < 4; r++) {
      float lv = __shfl(l_i[mi], (lane & 48) + quad * 4 + r, 64);
      il[mi][r] = 1.f / lv;
    }
#pragma unroll
  for (int mi = 0; mi < 2; mi++) {
    unsigned short* Op = O + (size_t)(b * SS + qbase + mi * 64 + wave * 16 + quad * 4) * DD + h * DH + l16;
#pragma unroll
    for (int f = 0; f < 8; f++)
#pragma unroll
      for (int r = 0; r < 4; r++)
        Op[(size_t)r * DD + f * 16] = f2bf(o[mi][f][r] * il[mi][r]);
  }
}

// -------------------------------------------------------------------------------
extern "C" void kernel_launch(void* const* d_in, const int* in_sizes, int n_in,
                              void* d_out, int out_size, void* d_ws, size_t ws_size,
                              hipStream_t stream) {
  const float* hs      = (const float*)d_in[0];
  const float* wqkv    = (const float*)d_in[1];
  const float* wout    = (const float*)d_in[2];
  const float* q_scale = (const float*)d_in[3];
  const float* k_scale = (const float*)d_in[4];
  const float* cosc    = (const float*)d_in[5];
  const float* sinc    = (const float*)d_in[6];
  // d_in[7] = attention_mask: causal, recomputed from indices — not read.
  float* out = (float*)d_out;

  unsigned short* ws = (unsigned short*)d_ws;
  unsigned short* wqkvT = ws;                        // 6144*4096 = 25165824
  unsigned short* woutT = wqkvT + 25165824;          // 4096*4096 = 16777216
  unsigned short* hsb   = woutT + 16777216;          // 4096*4096 = 16777216
  unsigned short* qkv   = hsb + 16777216;            // 4096*6144 = 25165824
  unsigned short* qrope = wqkvT;                     // alias (wqkvT dead after GEMM1)
  unsigned short* krope = wqkvT + 16777216;
  unsigned short* vT    = wqkvT + 16777216 + 4194304;
  unsigned short* attno = hsb;                       // alias (hsb dead after GEMM1)

  cast_bf16_kernel<<<16384, 256, 0, stream>>>(hs, hsb, 4194304);
  transpose_cast_kernel<<<dim3(192, 128), dim3(32, 8), 0, stream>>>(wqkv, wqkvT, 4096, 6144);
  transpose_cast_kernel<<<dim3(128, 128), dim3(32, 8), 0, stream>>>(wout, woutT, 4096, 4096);
  gemm_bt<unsigned short><<<dim3(32, 48), 256, 0, stream>>>(hsb, wqkvT, qkv, 4096, 6144, 4096);
  rmsnorm_rope_kernel<<<4096, 256, 0, stream>>>(qkv, q_scale, k_scale, cosc, sinc,
                                                qrope, krope);
  transpose_v_kernel<<<dim3(64, 4, 16), dim3(32, 8), 0, stream>>>(qkv, vT);
  flash_attn<<<dim3(64, 16), 256, 0, stream>>>(qrope, krope, vT, attno);
  gemm_bt<float><<<dim3(32, 32), 256, 0, stream>>>(attno, woutT, out, 4096, 4096, 4096);
}